// Round 3
// baseline (62.804 us; speedup 1.0000x reference)
//
#include <hip/hip_runtime.h>
#include <hip/hip_bf16.h>

#define TOKENS 16384
#define NEXP 8
#define INF 512
#define OUTF 512

#define BM 128
#define BN 128
#define BK 64
#define MAXMT 40   // max m-tiles per expert; counts ~2048+-42, 5120 is >70 sigma

using f32x4 = __attribute__((ext_vector_type(4))) float;
using bfrag = __attribute__((ext_vector_type(8))) __bf16;
using s8v   = __attribute__((ext_vector_type(8))) short;

// fp32 -> bf16 RNE
__device__ __forceinline__ short f2bf(float f) {
  union { float f; unsigned u; } v; v.f = f;
  unsigned r = v.u + 0x7fffu + ((v.u >> 16) & 1u);
  return (short)(r >> 16);
}

__device__ __forceinline__ void gload16(const void* g, void* l) {
  __builtin_amdgcn_global_load_lds(
      (const __attribute__((address_space(1))) unsigned int*)g,
      (__attribute__((address_space(3))) unsigned int*)l, 16, 0, 0);
}

// weight fp32 -> bf16 (contiguous [E][O][I]); also zeroes the scatter cursor
__global__ void k_convw(const float* __restrict__ w, s8v* __restrict__ wb,
                        int* __restrict__ cursor) {
  if (blockIdx.x == 0 && threadIdx.x < NEXP) cursor[threadIdx.x] = 0;
  int idx = blockIdx.x * 256 + threadIdx.x;
  const float4* src = (const float4*)w + (size_t)idx * 2;
  float4 a = src[0], b = src[1];
  s8v p;
  p[0] = f2bf(a.x); p[1] = f2bf(a.y); p[2] = f2bf(a.z); p[3] = f2bf(a.w);
  p[4] = f2bf(b.x); p[5] = f2bf(b.y); p[6] = f2bf(b.z); p[7] = f2bf(b.w);
  wb[idx] = p;
}

// Bucket tokens by expert (block-aggregated atomics).
__global__ void k_scatter(const int* __restrict__ gate, int* __restrict__ cursor,
                          int* __restrict__ perm) {
  __shared__ int lc[NEXP], lb[NEXP];
  int tid = threadIdx.x;
  if (tid < NEXP) lc[tid] = 0;
  __syncthreads();
  int t = blockIdx.x * 256 + tid;
  int e = gate[t];
  int ls = atomicAdd(&lc[e], 1);
  __syncthreads();
  if (tid < NEXP) lb[tid] = lc[tid] ? atomicAdd(&cursor[tid], lc[tid]) : 0;
  __syncthreads();
  perm[e * TOKENS + lb[e] + ls] = t;
}

// Grouped GEMM, 2-phase double-buffered:
//   A: gathered fp32 token rows -> regs (issued early) -> cvt bf16 -> swizzled
//      ds_write_b128 (T14 async-stage split).
//   B: pre-converted bf16 weight via global_load_lds, source-swizzled (rule #21).
// One __syncthreads per K-step; next tile's loads issued before current compute.
__global__ __launch_bounds__(256, 2)
void moe_gemm(const float* __restrict__ inp, const short* __restrict__ wb,
              const int* __restrict__ cursor, const int* __restrict__ perm,
              float* __restrict__ out) {
  const int nt = blockIdx.x;   // 0..3
  const int mt = blockIdx.y;   // 0..MAXMT-1
  const int e  = blockIdx.z;   // 0..7
  const int cnt = cursor[e];
  if (mt * BM >= cnt) return;
  const int m_valid = min(BM, cnt - mt * BM);
  const int* pbase = perm + e * TOKENS + mt * BM;

  __shared__ __align__(16) short As[2][BM * BK];  // 2 x 16 KB, chunk-swizzled
  __shared__ __align__(16) short Bs[2][BN * BK];  // 2 x 16 KB, chunk-swizzled
  __shared__ int toks[BM];

  const int tid = threadIdx.x;
  if (tid < BM) toks[tid] = pbase[(tid < m_valid) ? tid : 0];
  __syncthreads();

  const int lane = tid & 63;
  const int wid  = tid >> 6;
  const int wr = wid >> 1, wc = wid & 1;
  const int lr = lane & 15;
  const int lg = lane >> 4;

  // ---- A reg-stage geometry: thread = (row, half); 8 float4 -> 4 s8v chunks
  const int arow  = tid >> 1;
  const int ahalf = tid & 1;
  const float* aptr = inp + (size_t)toks[arow] * INF + ahalf * 32;
  int awoff[4];
#pragma unroll
  for (int j = 0; j < 4; j++)
    awoff[j] = arow * 128 + ((((ahalf * 4 + j) ^ (arow & 7))) * 16);

  // ---- B gload geometry: site s covers chunk s*256+tid; source pre-swizzled
  const short* wbase = wb + ((size_t)e * OUTF + (size_t)(nt * BN)) * INF;
  const short* bgp[4];
#pragma unroll
  for (int s = 0; s < 4; s++) {
    int row  = s * 32 + (tid >> 3);
    int clog = (tid & 7) ^ (row & 7);
    bgp[s] = wbase + (size_t)row * INF + clog * 8;
  }

  f32x4 acc[4][4];
#pragma unroll
  for (int i = 0; i < 4; i++)
#pragma unroll
    for (int j = 0; j < 4; j++) acc[i][j] = (f32x4)0.0f;

#define STAGE_B(buf, kk)                                                      \
  {                                                                           \
    _Pragma("unroll") for (int s = 0; s < 4; s++)                             \
        gload16(bgp[s] + (kk), (char*)&Bs[buf][0] + s * 4096 + wid * 1024);   \
  }
#define LOAD_A(ar, kk)                                                        \
  {                                                                           \
    _Pragma("unroll") for (int j = 0; j < 8; j++)                             \
        ar[j] = *(const float4*)(aptr + (kk) + j * 4);                        \
  }
#define WRITE_A(buf, ar)                                                      \
  {                                                                           \
    _Pragma("unroll") for (int j2 = 0; j2 < 4; j2++) {                        \
      float4 lo = ar[2 * j2], hi = ar[2 * j2 + 1];                            \
      s8v p;                                                                  \
      p[0] = f2bf(lo.x); p[1] = f2bf(lo.y); p[2] = f2bf(lo.z);                \
      p[3] = f2bf(lo.w); p[4] = f2bf(hi.x); p[5] = f2bf(hi.y);                \
      p[6] = f2bf(hi.z); p[7] = f2bf(hi.w);                                   \
      *(s8v*)((char*)&As[buf][0] + awoff[j2]) = p;                            \
    }                                                                         \
  }

  // ---- prologue: stage tile 0 into buf 0
  {
    float4 ar[8];
    LOAD_A(ar, 0);
    STAGE_B(0, 0);
    WRITE_A(0, ar);
  }
  __syncthreads();

  for (int t = 0; t < INF / BK; t++) {
    const int cur = t & 1;
    float4 ar[8];
    if (t < INF / BK - 1) {          // issue next tile's loads FIRST (T14/T3)
      LOAD_A(ar, (t + 1) * BK);
      STAGE_B(cur ^ 1, (t + 1) * BK);
    }

    // ---- compute current tile: 2 ks x 4x4 frags = 32 MFMA / wave
#pragma unroll
    for (int ks = 0; ks < 2; ks++) {
      bfrag af[4], bfv[4];
#pragma unroll
      for (int i = 0; i < 4; i++) {
        int row = wr * 64 + i * 16 + lr;
        int off = row * 128 + (((ks * 4 + lg) ^ (row & 7)) * 16);
        af[i] = *(const bfrag*)((const char*)&As[cur][0] + off);
      }
#pragma unroll
      for (int j = 0; j < 4; j++) {
        int row = wc * 64 + j * 16 + lr;
        int off = row * 128 + (((ks * 4 + lg) ^ (row & 7)) * 16);
        bfv[j] = *(const bfrag*)((const char*)&Bs[cur][0] + off);
      }
#pragma unroll
      for (int i = 0; i < 4; i++)
#pragma unroll
        for (int j = 0; j < 4; j++)
          acc[i][j] = __builtin_amdgcn_mfma_f32_16x16x32_bf16(af[i], bfv[j],
                                                              acc[i][j], 0, 0, 0);
    }

    if (t < INF / BK - 1) {
      WRITE_A(cur ^ 1, ar);          // vmcnt wait auto-inserted before cvt
      __syncthreads();               // drains B DMA + A writes; read-done fence
    }
  }

  // ---- epilogue: C/D col=lane&15, row=(lane>>4)*4+reg
#pragma unroll
  for (int i = 0; i < 4; i++) {
    int rbase = wr * 64 + i * 16 + lg * 4;
#pragma unroll
    for (int r = 0; r < 4; r++) {
      int rr = rbase + r;
      if (rr < m_valid) {
        float* orow = out + (size_t)toks[rr] * OUTF + nt * BN + wc * 64 + lr;
#pragma unroll
        for (int j = 0; j < 4; j++) orow[j * 16] = acc[i][j][r];
      }
    }
  }
#undef STAGE_B
#undef LOAD_A
#undef WRITE_A
}

extern "C" void kernel_launch(void* const* d_in, const int* in_sizes, int n_in,
                              void* d_out, int out_size, void* d_ws, size_t ws_size,
                              hipStream_t stream) {
  (void)in_sizes; (void)n_in; (void)out_size; (void)ws_size;
  const float* inp    = (const float*)d_in[0];
  const int*   gate   = (const int*)d_in[1];
  const float* weight = (const float*)d_in[2];
  float* out = (float*)d_out;

  int*   cursor = (int*)d_ws;                          // 8 ints
  int*   perm   = (int*)((char*)d_ws + 1024);          // 512 KB
  short* wbf    = (short*)((char*)d_ws + (1 << 20));   // 4 MB bf16 weight

  k_convw<<<(NEXP * OUTF * INF) / (256 * 8), 256, 0, stream>>>(weight, (s8v*)wbf,
                                                               cursor);
  k_scatter<<<TOKENS / 256, 256, 0, stream>>>(gate, cursor, perm);
  dim3 grid(OUTF / BN, MAXMT, NEXP);
  moe_gemm<<<grid, 256, 0, stream>>>(inp, wbf, cursor, perm, out);
}

// Round 4
// 35.396 us; speedup vs baseline: 1.7743x; 1.7743x over previous
//
#include <hip/hip_runtime.h>
#include <hip/hip_bf16.h>

#define TOKENS 16384
#define NEXP 8
#define INF 512
#define OUTF 512

#define BM 128
#define BN 128
#define BK 64
#define MAXMT 40   // counts ~2048±42 (σ); 5120 is >70σ — safe cap
#define NSTEP (INF / BK)

using f32x4 = __attribute__((ext_vector_type(4))) float;
using bfrag = __attribute__((ext_vector_type(8))) __bf16;
using s8v   = __attribute__((ext_vector_type(8))) short;
using s4v   = __attribute__((ext_vector_type(4))) short;

// fp32 -> bf16 RNE
__device__ __forceinline__ short f2bf(float f) {
  union { float f; unsigned u; } v; v.f = f;
  unsigned r = v.u + 0x7fffu + ((v.u >> 16) & 1u);
  return (short)(r >> 16);
}

__device__ __forceinline__ void gload16(const void* g, void* l) {
  __builtin_amdgcn_global_load_lds(
      (const __attribute__((address_space(1))) unsigned int*)g,
      (__attribute__((address_space(3))) unsigned int*)l, 16, 0, 0);
}

// weight fp32 -> bf16 (contiguous [E][O][I]); also zeroes the scatter cursor
__global__ void k_convw(const float* __restrict__ w, s8v* __restrict__ wb,
                        int* __restrict__ cursor) {
  if (blockIdx.x == 0 && threadIdx.x < NEXP) cursor[threadIdx.x] = 0;
  int idx = blockIdx.x * 256 + threadIdx.x;
  const float4* src = (const float4*)w + (size_t)idx * 2;
  float4 a = src[0], b = src[1];
  s8v p;
  p[0] = f2bf(a.x); p[1] = f2bf(a.y); p[2] = f2bf(a.z); p[3] = f2bf(a.w);
  p[4] = f2bf(b.x); p[5] = f2bf(b.y); p[6] = f2bf(b.z); p[7] = f2bf(b.w);
  wb[idx] = p;
}

// Bucket tokens by expert (block-aggregated atomics).
__global__ void k_scatter(const int* __restrict__ gate, int* __restrict__ cursor,
                          int* __restrict__ perm) {
  __shared__ int lc[NEXP], lb[NEXP];
  int tid = threadIdx.x;
  if (tid < NEXP) lc[tid] = 0;
  __syncthreads();
  int t = blockIdx.x * 256 + tid;
  int e = gate[t];
  int ls = atomicAdd(&lc[e], 1);
  __syncthreads();
  if (tid < NEXP) lb[tid] = lc[tid] ? atomicAdd(&cursor[tid], lc[tid]) : 0;
  __syncthreads();
  perm[e * TOKENS + lb[e] + ls] = t;
}

// Grouped GEMM. XCD-affine 1D grid: e = bid&7 (-> XCD e under %8 round-robin),
// nt = (bid>>3)&3 (A-panel siblings 8 apart -> same XCD), mt = bid>>5.
// A: gathered fp32 rows -> regs (issued early) -> cvt bf16 -> swizzled ds_write
//    into a SINGLE 16KB buffer (writes only after the read-done barrier).
// B: bf16 weight via global_load_lds into a DOUBLE 2x16KB buffer, source
//    pre-swizzled (rule #21: linear dest + inverse-swz source + swz read).
__global__ __launch_bounds__(256, 3)
void moe_gemm(const float* __restrict__ inp, const short* __restrict__ wb,
              const int* __restrict__ cursor, const int* __restrict__ perm,
              float* __restrict__ out) {
  const int bid = blockIdx.x;
  const int e  = bid & 7;
  const int nt = (bid >> 3) & 3;
  const int mt = bid >> 5;
  const int cnt = cursor[e];
  if (mt * BM >= cnt) return;
  const int m_valid = min(BM, cnt - mt * BM);
  const int* pbase = perm + e * TOKENS + mt * BM;

  __shared__ __align__(16) short As[BM * BK];      // 16 KB, single buffer
  __shared__ __align__(16) short Bs[2][BN * BK];   // 2 x 16 KB
  __shared__ int toks[BM];

  const int tid = threadIdx.x;
  if (tid < BM) toks[tid] = pbase[(tid < m_valid) ? tid : 0];
  __syncthreads();

  const int lane = tid & 63;
  const int wid  = tid >> 6;
  const int wr = wid >> 1, wc = wid & 1;
  const int lr = lane & 15;
  const int lg = lane >> 4;

  // ---- A reg-stage geometry: site s covers rows s*16..s*16+15; 16 lanes/row,
  //      each lane one float4 granule g = tid&15 (natural load, coalesced 256B/row)
  const float* aptr[8];
  int awoff[8];
  {
    const int g = tid & 15;
#pragma unroll
    for (int s = 0; s < 8; s++) {
      int row = s * 16 + (tid >> 4);
      aptr[s] = inp + (size_t)toks[row] * INF + g * 4;
      awoff[s] = row * 128 + (((g >> 1) ^ (row & 7)) * 16) + (g & 1) * 8;
    }
  }

  // ---- B DMA geometry: site s covers chunk s*256+tid; source pre-swizzled
  const short* wbase = wb + ((size_t)e * OUTF + (size_t)(nt * BN)) * INF;
  const short* bgp[4];
#pragma unroll
  for (int s = 0; s < 4; s++) {
    int row  = s * 32 + (tid >> 3);
    int clog = (tid & 7) ^ (row & 7);
    bgp[s] = wbase + (size_t)row * INF + clog * 8;
  }

  f32x4 acc[4][4];
#pragma unroll
  for (int i = 0; i < 4; i++)
#pragma unroll
    for (int j = 0; j < 4; j++) acc[i][j] = (f32x4)0.0f;

#define STAGE_B(buf, kk)                                                      \
  {                                                                           \
    _Pragma("unroll") for (int s = 0; s < 4; s++)                             \
        gload16(bgp[s] + (kk), (char*)&Bs[buf][0] + s * 4096 + wid * 1024);   \
  }
#define LOAD_A(ar, kk)                                                        \
  {                                                                           \
    _Pragma("unroll") for (int s = 0; s < 8; s++)                             \
        ar[s] = *(const float4*)(aptr[s] + (kk));                             \
  }
#define WRITE_A(ar)                                                           \
  {                                                                           \
    _Pragma("unroll") for (int s = 0; s < 8; s++) {                           \
      s4v p;                                                                  \
      p[0] = f2bf(ar[s].x); p[1] = f2bf(ar[s].y);                             \
      p[2] = f2bf(ar[s].z); p[3] = f2bf(ar[s].w);                             \
      *(s4v*)((char*)As + awoff[s]) = p;                                      \
    }                                                                         \
  }

  // ---- prologue: stage tile 0
  {
    float4 ar[8];
    LOAD_A(ar, 0);
    STAGE_B(0, 0);
    WRITE_A(ar);
  }
  __syncthreads();

  for (int t = 0; t < NSTEP; t++) {
    const int cur = t & 1;
    float4 ar[8];
    if (t < NSTEP - 1) {              // issue next tile's loads FIRST
      LOAD_A(ar, (t + 1) * BK);
      STAGE_B(cur ^ 1, (t + 1) * BK);
    }

    // ---- compute current tile: 2 ks x 4x4 frags = 32 MFMA / wave
#pragma unroll
    for (int ks = 0; ks < 2; ks++) {
      bfrag af[4], bfv[4];
#pragma unroll
      for (int i = 0; i < 4; i++) {
        int row = wr * 64 + i * 16 + lr;
        int off = row * 128 + (((ks * 4 + lg) ^ (row & 7)) * 16);
        af[i] = *(const bfrag*)((const char*)As + off);
      }
#pragma unroll
      for (int j = 0; j < 4; j++) {
        int row = wc * 64 + j * 16 + lr;
        int off = row * 128 + (((ks * 4 + lg) ^ (row & 7)) * 16);
        bfv[j] = *(const bfrag*)((const char*)&Bs[cur][0] + off);
      }
#pragma unroll
      for (int i = 0; i < 4; i++)
#pragma unroll
        for (int j = 0; j < 4; j++)
          acc[i][j] = __builtin_amdgcn_mfma_f32_16x16x32_bf16(af[i], bfv[j],
                                                              acc[i][j], 0, 0, 0);
    }

    if (t < NSTEP - 1) {
      __syncthreads();   // all reads of As/Bs[cur] done; drains A-loads + B-DMA
      WRITE_A(ar);       // overwrite single A buffer (safe post-barrier)
      __syncthreads();   // A writes visible; Bs[cur^1] resident
    }
  }

  // ---- epilogue: C/D col=lane&15, row=(lane>>4)*4+reg
#pragma unroll
  for (int i = 0; i < 4; i++) {
    int rbase = wr * 64 + i * 16 + lg * 4;
#pragma unroll
    for (int r = 0; r < 4; r++) {
      int rr = rbase + r;
      if (rr < m_valid) {
        float* orow = out + (size_t)toks[rr] * OUTF + nt * BN + wc * 64 + lr;
#pragma unroll
        for (int j = 0; j < 4; j++) orow[j * 16] = acc[i][j][r];
      }
    }
  }
#undef STAGE_B
#undef LOAD_A
#undef WRITE_A
}

extern "C" void kernel_launch(void* const* d_in, const int* in_sizes, int n_in,
                              void* d_out, int out_size, void* d_ws, size_t ws_size,
                              hipStream_t stream) {
  (void)in_sizes; (void)n_in; (void)out_size; (void)ws_size;
  const float* inp    = (const float*)d_in[0];
  const int*   gate   = (const int*)d_in[1];
  const float* weight = (const float*)d_in[2];
  float* out = (float*)d_out;

  int*   cursor = (int*)d_ws;                          // 8 ints
  int*   perm   = (int*)((char*)d_ws + 1024);          // 512 KB
  short* wbf    = (short*)((char*)d_ws + (1 << 20));   // 4.2 MB bf16 weight

  k_convw<<<(NEXP * OUTF * INF) / (256 * 8), 256, 0, stream>>>(weight, (s8v*)wbf,
                                                               cursor);
  k_scatter<<<TOKENS / 256, 256, 0, stream>>>(gate, cursor, perm);
  moe_gemm<<<NEXP * 4 * MAXMT, 256, 0, stream>>>(inp, wbf, cursor, perm, out);
}